// Round 1
// baseline (966.927 us; speedup 1.0000x reference)
//
#include <hip/hip_runtime.h>
#include <stdint.h>

typedef __attribute__((ext_vector_type(4))) float f32x4;
typedef __attribute__((ext_vector_type(8))) short bf16x8;

#define MFMA(a, b, c) __builtin_amdgcn_mfma_f32_16x16x32_bf16(a, b, c, 0, 0, 0)

__device__ __forceinline__ short f2bf(float f) {
    unsigned u = __builtin_bit_cast(unsigned, f);
    u = (u + 0x7fffu + ((u >> 16) & 1u)) >> 16;
    return (short)u;
}

__device__ __forceinline__ void g2l16(const void* g, void* l) {
    __builtin_amdgcn_global_load_lds(
        (const __attribute__((address_space(1))) unsigned*)g,
        (__attribute__((address_space(3))) unsigned*)l, 16, 0, 0);
}

// ---------------- fp32 -> bf16 convert (8 elems / thread) ----------------
__global__ void cvt_bf16_kernel(const float* __restrict__ src,
                                short* __restrict__ dst, int n8) {
    int i = blockIdx.x * blockDim.x + threadIdx.x;
    if (i >= n8) return;
    const f32x4* s = (const f32x4*)src;
    f32x4 a = s[2 * i], b = s[2 * i + 1];
    bf16x8 o;
    o[0] = f2bf(a[0]); o[1] = f2bf(a[1]); o[2] = f2bf(a[2]); o[3] = f2bf(a[3]);
    o[4] = f2bf(b[0]); o[5] = f2bf(b[1]); o[6] = f2bf(b[2]); o[7] = f2bf(b[3]);
    ((bf16x8*)dst)[i] = o;
}

// ---------------- GEMM1: qkv = X @ Wi^T + bi, scatter to q/k/vt ----------
// A [4096,1024] bf16, W [3072,1024] bf16 (row = out feature), K = 1024.
// 128x128 tile, 4 waves, BK=32, global_load_lds width-16 staging (m97).
__global__ __launch_bounds__(256, 2) void gemm_qkv_kernel(
    const short* __restrict__ A, const short* __restrict__ W,
    const float* __restrict__ bias,
    short* __restrict__ qb, short* __restrict__ kb, short* __restrict__ vtb) {
    __shared__ short As[128 * 32];
    __shared__ short Bs[128 * 32];
    const int tid = threadIdx.x;
    const int wave = tid >> 6, lane = tid & 63;
    const int al = lane >> 4, ac = lane & 15;
    const int m0 = blockIdx.x * 128;
    const int n0 = blockIdx.y * 128;
    const int wm = wave & 1, wn = wave >> 1;

    const int crow = tid >> 2, ccol = (tid & 3) * 8;
    const short* Ag0 = A + (m0 + crow) * 1024 + ccol;
    const short* Ag1 = A + (m0 + crow + 64) * 1024 + ccol;
    const short* Wg0 = W + (n0 + crow) * 1024 + ccol;
    const short* Wg1 = W + (n0 + crow + 64) * 1024 + ccol;
    short* lA0 = &As[wave * 512];
    short* lA1 = &As[2048 + wave * 512];
    short* lB0 = &Bs[wave * 512];
    short* lB1 = &Bs[2048 + wave * 512];

    f32x4 acc[4][4];
#pragma unroll
    for (int mi = 0; mi < 4; mi++)
#pragma unroll
        for (int ni = 0; ni < 4; ni++) acc[mi][ni] = (f32x4){0.f, 0.f, 0.f, 0.f};

    for (int k0 = 0; k0 < 1024; k0 += 32) {
        __syncthreads();
        g2l16(Ag0 + k0, lA0);
        g2l16(Ag1 + k0, lA1);
        g2l16(Wg0 + k0, lB0);
        g2l16(Wg1 + k0, lB1);
        __syncthreads();
        bf16x8 af[4], bf[4];
#pragma unroll
        for (int i = 0; i < 4; i++) {
            af[i] = *(const bf16x8*)&As[(wm * 64 + i * 16 + ac) * 32 + al * 8];
            bf[i] = *(const bf16x8*)&Bs[(wn * 64 + i * 16 + ac) * 32 + al * 8];
        }
#pragma unroll
        for (int mi = 0; mi < 4; mi++)
#pragma unroll
            for (int ni = 0; ni < 4; ni++)
                acc[mi][ni] = MFMA(af[mi], bf[ni], acc[mi][ni]);
    }

    const int which = (n0 + wn * 64) >> 10;  // 0=q, 1=k, 2=v (uniform per wave)
#pragma unroll
    for (int mi = 0; mi < 4; mi++) {
#pragma unroll
        for (int ni = 0; ni < 4; ni++) {
            const int col = n0 + wn * 64 + ni * 16 + ac;
            const int e = col & 1023;
            const int h = e >> 6, d = e & 63;
            const float bv = bias[col];
#pragma unroll
            for (int r = 0; r < 4; r++) {
                const int row = m0 + wm * 64 + mi * 16 + al * 4 + r;
                const int b = row >> 11, l = row & 2047;
                const int bh = b * 16 + h;
                const float v = acc[mi][ni][r] + bv;
                if (which == 0)
                    qb[(bh * 2048 + l) * 64 + d] = f2bf(v * 0.125f);
                else if (which == 1)
                    kb[(bh * 2048 + l) * 64 + d] = f2bf(v);
                else
                    vtb[(bh * 64 + d) * 2048 + l] = f2bf(v);
            }
        }
    }
}

// ---------------- Fused flash attention with streamed bias ----------------
// Block: 64 q-rows of one (b,h); 4 waves x 16 rows; k-blocks of 64.
__global__ __launch_bounds__(256, 4) void attn_kernel(
    const short* __restrict__ Qb, const short* __restrict__ Kb,
    const short* __restrict__ Vtb, const float* __restrict__ bias,
    short* __restrict__ Ctx) {
    __shared__ short Qs[64 * 72];
    __shared__ short Ks[64 * 72];
    __shared__ short Vs[64 * 72];
    __shared__ short Ps[4][16 * 72];
    const int tid = threadIdx.x;
    const int wave = tid >> 6, lane = tid & 63;
    const int al = lane >> 4, ac = lane & 15;
    const int q0 = blockIdx.x * 64;
    const int bh = blockIdx.y;
    const long long kvbase = (long long)bh * (2048 * 64);

    const int sr = tid >> 3, sg = (tid & 7) * 8;

    *(bf16x8*)&Qs[sr * 72 + sg] = *(const bf16x8*)&Qb[kvbase + (q0 + sr) * 64 + sg];
    *(bf16x8*)&Qs[(sr + 32) * 72 + sg] =
        *(const bf16x8*)&Qb[kvbase + (q0 + sr + 32) * 64 + sg];
    __syncthreads();
    const bf16x8 qf0 = *(const bf16x8*)&Qs[(wave * 16 + ac) * 72 + al * 8];
    const bf16x8 qf1 = *(const bf16x8*)&Qs[(wave * 16 + ac) * 72 + al * 8 + 32];

    float m_i[4], l_i[4];
    f32x4 o[4];
#pragma unroll
    for (int r = 0; r < 4; r++) { m_i[r] = -1e30f; l_i[r] = 0.f; }
#pragma unroll
    for (int ni = 0; ni < 4; ni++) o[ni] = (f32x4){0.f, 0.f, 0.f, 0.f};

    const float L2E = 1.44269504088896340736f;
    const float* biasrow =
        bias + ((long long)bh * 2048 + q0 + wave * 16 + al * 4) * 2048;

    for (int kb = 0; kb < 32; ++kb) {
        const int k0 = kb * 64;
        __syncthreads();
        *(bf16x8*)&Ks[sr * 72 + sg] =
            *(const bf16x8*)&Kb[kvbase + (k0 + sr) * 64 + sg];
        *(bf16x8*)&Ks[(sr + 32) * 72 + sg] =
            *(const bf16x8*)&Kb[kvbase + (k0 + sr + 32) * 64 + sg];
        *(bf16x8*)&Vs[sr * 72 + sg] =
            *(const bf16x8*)&Vtb[kvbase + sr * 2048 + k0 + sg];
        *(bf16x8*)&Vs[(sr + 32) * 72 + sg] =
            *(const bf16x8*)&Vtb[kvbase + (sr + 32) * 2048 + k0 + sg];
        __syncthreads();

        f32x4 s[4];
#pragma unroll
        for (int ni = 0; ni < 4; ni++) {
            const bf16x8 kf0 = *(const bf16x8*)&Ks[(ni * 16 + ac) * 72 + al * 8];
            const bf16x8 kf1 =
                *(const bf16x8*)&Ks[(ni * 16 + ac) * 72 + al * 8 + 32];
            s[ni] = MFMA(qf0, kf0, ((f32x4){0.f, 0.f, 0.f, 0.f}));
            s[ni] = MFMA(qf1, kf1, s[ni]);
        }
        float mloc[4] = {-1e30f, -1e30f, -1e30f, -1e30f};
#pragma unroll
        for (int ni = 0; ni < 4; ni++)
#pragma unroll
            for (int r = 0; r < 4; r++) {
                float v = (s[ni][r] + biasrow[r * 2048 + k0 + ni * 16 + ac]) * L2E;
                s[ni][r] = v;
                mloc[r] = fmaxf(mloc[r], v);
            }
#pragma unroll
        for (int r = 0; r < 4; r++) {
#pragma unroll
            for (int off = 1; off < 16; off <<= 1)
                mloc[r] = fmaxf(mloc[r], __shfl_xor(mloc[r], off));
            const float mn = fmaxf(m_i[r], mloc[r]);
            const float a = __builtin_exp2f(m_i[r] - mn);
            m_i[r] = mn;
            l_i[r] *= a;
#pragma unroll
            for (int ni = 0; ni < 4; ni++) o[ni][r] *= a;
        }
        float rs[4] = {0.f, 0.f, 0.f, 0.f};
#pragma unroll
        for (int ni = 0; ni < 4; ni++)
#pragma unroll
            for (int r = 0; r < 4; r++) {
                const float p = __builtin_exp2f(s[ni][r] - m_i[r]);
                rs[r] += p;
                Ps[wave][(al * 4 + r) * 72 + ni * 16 + ac] = f2bf(p);
            }
#pragma unroll
        for (int r = 0; r < 4; r++) {
#pragma unroll
            for (int off = 1; off < 16; off <<= 1) rs[r] += __shfl_xor(rs[r], off);
            l_i[r] += rs[r];
        }
        const bf16x8 pf0 = *(const bf16x8*)&Ps[wave][ac * 72 + al * 8];
        const bf16x8 pf1 = *(const bf16x8*)&Ps[wave][ac * 72 + al * 8 + 32];
#pragma unroll
        for (int ni = 0; ni < 4; ni++) {
            const bf16x8 vf0 = *(const bf16x8*)&Vs[(ni * 16 + ac) * 72 + al * 8];
            const bf16x8 vf1 =
                *(const bf16x8*)&Vs[(ni * 16 + ac) * 72 + al * 8 + 32];
            o[ni] = MFMA(pf0, vf0, o[ni]);
            o[ni] = MFMA(pf1, vf1, o[ni]);
        }
    }

    const int b = bh >> 4, h = bh & 15;
#pragma unroll
    for (int r = 0; r < 4; r++) {
        const float inv = 1.f / l_i[r];
        const int qrow = q0 + wave * 16 + al * 4 + r;
#pragma unroll
        for (int ni = 0; ni < 4; ni++) {
            const int d = ni * 16 + ac;
            Ctx[((long long)(b * 2048 + qrow)) * 1024 + h * 64 + d] =
                f2bf(o[ni][r] * inv);
        }
    }
}

// ---------------- GEMM2: out = Ctx @ Wo^T + bo (fp32 out) ----------------
__global__ __launch_bounds__(256, 2) void gemm_out_kernel(
    const short* __restrict__ A, const short* __restrict__ W,
    const float* __restrict__ bias, float* __restrict__ out) {
    __shared__ short As[128 * 32];
    __shared__ short Bs[128 * 32];
    const int tid = threadIdx.x;
    const int wave = tid >> 6, lane = tid & 63;
    const int al = lane >> 4, ac = lane & 15;
    const int m0 = blockIdx.x * 128;
    const int n0 = blockIdx.y * 128;
    const int wm = wave & 1, wn = wave >> 1;

    const int crow = tid >> 2, ccol = (tid & 3) * 8;
    const short* Ag0 = A + (m0 + crow) * 1024 + ccol;
    const short* Ag1 = A + (m0 + crow + 64) * 1024 + ccol;
    const short* Wg0 = W + (n0 + crow) * 1024 + ccol;
    const short* Wg1 = W + (n0 + crow + 64) * 1024 + ccol;
    short* lA0 = &As[wave * 512];
    short* lA1 = &As[2048 + wave * 512];
    short* lB0 = &Bs[wave * 512];
    short* lB1 = &Bs[2048 + wave * 512];

    f32x4 acc[4][4];
#pragma unroll
    for (int mi = 0; mi < 4; mi++)
#pragma unroll
        for (int ni = 0; ni < 4; ni++) acc[mi][ni] = (f32x4){0.f, 0.f, 0.f, 0.f};

    for (int k0 = 0; k0 < 1024; k0 += 32) {
        __syncthreads();
        g2l16(Ag0 + k0, lA0);
        g2l16(Ag1 + k0, lA1);
        g2l16(Wg0 + k0, lB0);
        g2l16(Wg1 + k0, lB1);
        __syncthreads();
        bf16x8 af[4], bf[4];
#pragma unroll
        for (int i = 0; i < 4; i++) {
            af[i] = *(const bf16x8*)&As[(wm * 64 + i * 16 + ac) * 32 + al * 8];
            bf[i] = *(const bf16x8*)&Bs[(wn * 64 + i * 16 + ac) * 32 + al * 8];
        }
#pragma unroll
        for (int mi = 0; mi < 4; mi++)
#pragma unroll
            for (int ni = 0; ni < 4; ni++)
                acc[mi][ni] = MFMA(af[mi], bf[ni], acc[mi][ni]);
    }

#pragma unroll
    for (int mi = 0; mi < 4; mi++) {
#pragma unroll
        for (int ni = 0; ni < 4; ni++) {
            const int col = n0 + wn * 64 + ni * 16 + ac;
            const float bv = bias[col];
#pragma unroll
            for (int r = 0; r < 4; r++) {
                const int row = m0 + wm * 64 + mi * 16 + al * 4 + r;
                out[row * 1024 + col] = acc[mi][ni][r] + bv;
            }
        }
    }
}

extern "C" void kernel_launch(void* const* d_in, const int* in_sizes, int n_in,
                              void* d_out, int out_size, void* d_ws,
                              size_t ws_size, hipStream_t stream) {
    const float* X = (const float*)d_in[0];
    const float* keb = (const float*)d_in[1];
    const float* Wi = (const float*)d_in[2];
    const float* bi = (const float*)d_in[3];
    const float* Wo = (const float*)d_in[4];
    const float* bo = (const float*)d_in[5];
    float* out = (float*)d_out;

    char* ws = (char*)d_ws;
    short* Xb  = (short*)(ws);              //  8 MB  [4096,1024]
    short* Wib = (short*)(ws + 8388608);    //  6 MB  [3072,1024]
    short* Wob = (short*)(ws + 14680064);   //  2 MB  [1024,1024]
    short* Qb  = (short*)(ws + 16777216);   //  8 MB  [bh][l][d] (pre-scaled)
    short* Kb  = (short*)(ws + 25165824);   //  8 MB  [bh][l][d]
    short* Vtb = (short*)(ws + 33554432);   //  8 MB  [bh][d][l]
    short* Ctx = (short*)(ws + 41943040);   //  8 MB  [4096,1024]

    cvt_bf16_kernel<<<dim3(524288 / 256), 256, 0, stream>>>(X, Xb, 524288);
    cvt_bf16_kernel<<<dim3(393216 / 256), 256, 0, stream>>>(Wi, Wib, 393216);
    cvt_bf16_kernel<<<dim3(131072 / 256), 256, 0, stream>>>(Wo, Wob, 131072);
    gemm_qkv_kernel<<<dim3(32, 24), 256, 0, stream>>>(Xb, Wib, bi, Qb, Kb, Vtb);
    attn_kernel<<<dim3(32, 32), 256, 0, stream>>>(Qb, Kb, Vtb, keb, Ctx);
    gemm_out_kernel<<<dim3(32, 8), 256, 0, stream>>>(Ctx, Wob, bo, out);
}

// Round 2
// 805.383 us; speedup vs baseline: 1.2006x; 1.2006x over previous
//
#include <hip/hip_runtime.h>
#include <stdint.h>

typedef __attribute__((ext_vector_type(4))) float f32x4;
typedef __attribute__((ext_vector_type(8))) short bf16x8;
typedef __attribute__((ext_vector_type(4))) short bf16x4;

#define MFMA(a, b, c) __builtin_amdgcn_mfma_f32_16x16x32_bf16(a, b, c, 0, 0, 0)

__device__ __forceinline__ short f2bf(float f) {
    unsigned u = __builtin_bit_cast(unsigned, f);
    u = (u + 0x7fffu + ((u >> 16) & 1u)) >> 16;
    return (short)u;
}

__device__ __forceinline__ void g2l16(const void* g, void* l) {
    __builtin_amdgcn_global_load_lds(
        (const __attribute__((address_space(1))) unsigned*)g,
        (__attribute__((address_space(3))) unsigned*)l, 16, 0, 0);
}

// ---------------- fp32 -> bf16 convert (8 elems / thread) ----------------
__global__ void cvt_bf16_kernel(const float* __restrict__ src,
                                short* __restrict__ dst, int n8) {
    int i = blockIdx.x * blockDim.x + threadIdx.x;
    if (i >= n8) return;
    const f32x4* s = (const f32x4*)src;
    f32x4 a = s[2 * i], b = s[2 * i + 1];
    bf16x8 o;
    o[0] = f2bf(a[0]); o[1] = f2bf(a[1]); o[2] = f2bf(a[2]); o[3] = f2bf(a[3]);
    o[4] = f2bf(b[0]); o[5] = f2bf(b[1]); o[6] = f2bf(b[2]); o[7] = f2bf(b[3]);
    ((bf16x8*)dst)[i] = o;
}

// ---------------- GEMM1: qkv = X @ Wi^T + bi, scatter to q/k/vt ----------
__global__ __launch_bounds__(256, 2) void gemm_qkv_kernel(
    const short* __restrict__ A, const short* __restrict__ W,
    const float* __restrict__ bias,
    short* __restrict__ qb, short* __restrict__ kb, short* __restrict__ vtb) {
    __shared__ short As[128 * 32];
    __shared__ short Bs[128 * 32];
    __shared__ short scrS[4][16 * 24];  // per-wave epilogue repack, stride 24
    const int tid = threadIdx.x;
    const int wave = tid >> 6, lane = tid & 63;
    const int al = lane >> 4, ac = lane & 15;
    const int m0 = blockIdx.x * 128;
    const int n0 = blockIdx.y * 128;
    const int wm = wave & 1, wn = wave >> 1;

    const int crow = tid >> 2, ccol = (tid & 3) * 8;
    const short* Ag0 = A + (m0 + crow) * 1024 + ccol;
    const short* Ag1 = A + (m0 + crow + 64) * 1024 + ccol;
    const short* Wg0 = W + (n0 + crow) * 1024 + ccol;
    const short* Wg1 = W + (n0 + crow + 64) * 1024 + ccol;
    short* lA0 = &As[wave * 512];
    short* lA1 = &As[2048 + wave * 512];
    short* lB0 = &Bs[wave * 512];
    short* lB1 = &Bs[2048 + wave * 512];

    f32x4 acc[4][4];
#pragma unroll
    for (int mi = 0; mi < 4; mi++)
#pragma unroll
        for (int ni = 0; ni < 4; ni++) acc[mi][ni] = (f32x4){0.f, 0.f, 0.f, 0.f};

    for (int k0 = 0; k0 < 1024; k0 += 32) {
        __syncthreads();
        g2l16(Ag0 + k0, lA0);
        g2l16(Ag1 + k0, lA1);
        g2l16(Wg0 + k0, lB0);
        g2l16(Wg1 + k0, lB1);
        __syncthreads();
        bf16x8 af[4], bfr[4];
#pragma unroll
        for (int i = 0; i < 4; i++) {
            af[i] = *(const bf16x8*)&As[(wm * 64 + i * 16 + ac) * 32 + al * 8];
            bfr[i] = *(const bf16x8*)&Bs[(wn * 64 + i * 16 + ac) * 32 + al * 8];
        }
#pragma unroll
        for (int mi = 0; mi < 4; mi++)
#pragma unroll
            for (int ni = 0; ni < 4; ni++)
                acc[mi][ni] = MFMA(af[mi], bfr[ni], acc[mi][ni]);
    }

    // ---- epilogue: per-wave LDS repack -> 8B coalesced stores ----
    const int n0w = n0 + wn * 64;
    const int which = n0w >> 10;  // 0=q, 1=k, 2=v (wave-uniform)
    short* scr = scrS[wave];
    const int lr = lane >> 2;   // read-phase row 0..15
    const int lq = lane & 3;    // read-phase quad
    const int bglob = m0 >> 11; // batch (uniform per block)

#pragma unroll
    for (int mi = 0; mi < 4; mi++) {
#pragma unroll
        for (int ni = 0; ni < 4; ni++) {
            const int col0 = n0w + ni * 16;
            const float bvc = bias[col0 + ac];
            if (which == 2) {
                // transpose in LDS: scr[d=ac][l=al*4+r], packed b64 write
                bf16x4 pk;
#pragma unroll
                for (int r = 0; r < 4; r++) pk[r] = f2bf(acc[mi][ni][r] + bvc);
                *(bf16x4*)&scr[ac * 24 + al * 4] = pk;
                bf16x4 v4 = *(const bf16x4*)&scr[lr * 24 + lq * 4];
                const int colv = col0 + lr;
                const int e = colv & 1023;
                const int h = e >> 6, d = e & 63;
                const int row0 = m0 + wm * 64 + mi * 16 + lq * 4;
                const int l0 = row0 & 2047;
                *(bf16x4*)&vtb[(((bglob * 16 + h) * 64 + d) * 2048) + l0] = v4;
            } else {
                const float sc = (which == 0) ? 0.125f : 1.0f;
#pragma unroll
                for (int r = 0; r < 4; r++)
                    scr[(al * 4 + r) * 24 + ac] = f2bf((acc[mi][ni][r] + bvc) * sc);
                bf16x4 v4 = *(const bf16x4*)&scr[lr * 24 + lq * 4];
                const int col = col0 + lq * 4;
                const int e = col & 1023;
                const int h = e >> 6, d0 = e & 63;
                const int row = m0 + wm * 64 + mi * 16 + lr;
                const int l = row & 2047;
                short* dst = (which == 0) ? qb : kb;
                *(bf16x4*)&dst[(((bglob * 16 + h) * 2048 + l) * 64) + d0] = v4;
            }
        }
    }
}

// ---------------- Fused flash attention, fully pipelined ----------------
// Block: 64 q-rows of one (b,h); 4 waves x 16 rows; k-blocks of 64.
// K/V prefetched into registers one k-block ahead; bias prefetched into
// 16 registers one k-block ahead (issued after softmax, consumed next iter).
__global__ __launch_bounds__(256, 4) void attn_kernel(
    const short* __restrict__ Qb, const short* __restrict__ Kb,
    const short* __restrict__ Vtb, const float* __restrict__ bias,
    short* __restrict__ Ctx) {
    __shared__ short Qs[64 * 72];
    __shared__ short Ks[64 * 72];
    __shared__ short Vs[64 * 72];
    __shared__ short Ps[4][16 * 72];
    const int tid = threadIdx.x;
    const int wave = tid >> 6, lane = tid & 63;
    const int al = lane >> 4, ac = lane & 15;
    const int q0 = blockIdx.x * 64;
    const int bh = blockIdx.y;
    const long long kvbase = (long long)bh * (2048 * 64);

    const int sr = tid >> 3, sg = (tid & 7) * 8;

    *(bf16x8*)&Qs[sr * 72 + sg] = *(const bf16x8*)&Qb[kvbase + (q0 + sr) * 64 + sg];
    *(bf16x8*)&Qs[(sr + 32) * 72 + sg] =
        *(const bf16x8*)&Qb[kvbase + (q0 + sr + 32) * 64 + sg];
    __syncthreads();
    const bf16x8 qf0 = *(const bf16x8*)&Qs[(wave * 16 + ac) * 72 + al * 8];
    const bf16x8 qf1 = *(const bf16x8*)&Qs[(wave * 16 + ac) * 72 + al * 8 + 32];

    float m_i[4], l_i[4];
    f32x4 o[4];
#pragma unroll
    for (int r = 0; r < 4; r++) { m_i[r] = -1e30f; l_i[r] = 0.f; }
#pragma unroll
    for (int ni = 0; ni < 4; ni++) o[ni] = (f32x4){0.f, 0.f, 0.f, 0.f};

    const float L2E = 1.44269504088896340736f;
    const float* bp =
        bias + ((long long)bh * 2048 + q0 + wave * 16 + al * 4) * 2048 + ac;

    // ---- prologue: prefetch KV + bias for kb=0 ----
    bf16x8 kr0 = *(const bf16x8*)&Kb[kvbase + sr * 64 + sg];
    bf16x8 kr1 = *(const bf16x8*)&Kb[kvbase + (sr + 32) * 64 + sg];
    bf16x8 vr0 = *(const bf16x8*)&Vtb[kvbase + sr * 2048 + sg];
    bf16x8 vr1 = *(const bf16x8*)&Vtb[kvbase + (sr + 32) * 2048 + sg];
    float bc[16];
#pragma unroll
    for (int ni = 0; ni < 4; ni++)
#pragma unroll
        for (int r = 0; r < 4; r++) bc[ni * 4 + r] = bp[r * 2048 + ni * 16];

#pragma unroll 2
    for (int kbk = 0; kbk < 32; ++kbk) {
        __syncthreads();
        *(bf16x8*)&Ks[sr * 72 + sg] = kr0;
        *(bf16x8*)&Ks[(sr + 32) * 72 + sg] = kr1;
        *(bf16x8*)&Vs[sr * 72 + sg] = vr0;
        *(bf16x8*)&Vs[(sr + 32) * 72 + sg] = vr1;
        __syncthreads();

        const int k1 = (kbk + 1) * 64;
        if (kbk < 31) {
            kr0 = *(const bf16x8*)&Kb[kvbase + (k1 + sr) * 64 + sg];
            kr1 = *(const bf16x8*)&Kb[kvbase + (k1 + sr + 32) * 64 + sg];
            vr0 = *(const bf16x8*)&Vtb[kvbase + sr * 2048 + k1 + sg];
            vr1 = *(const bf16x8*)&Vtb[kvbase + (sr + 32) * 2048 + k1 + sg];
        }

        f32x4 s[4];
#pragma unroll
        for (int ni = 0; ni < 4; ni++) {
            const bf16x8 kf0 = *(const bf16x8*)&Ks[(ni * 16 + ac) * 72 + al * 8];
            const bf16x8 kf1 =
                *(const bf16x8*)&Ks[(ni * 16 + ac) * 72 + al * 8 + 32];
            s[ni] = MFMA(qf0, kf0, ((f32x4){0.f, 0.f, 0.f, 0.f}));
            s[ni] = MFMA(qf1, kf1, s[ni]);
        }
        float mloc[4] = {-1e30f, -1e30f, -1e30f, -1e30f};
#pragma unroll
        for (int ni = 0; ni < 4; ni++)
#pragma unroll
            for (int r = 0; r < 4; r++) {
                float v = (s[ni][r] + bc[ni * 4 + r]) * L2E;
                s[ni][r] = v;
                mloc[r] = fmaxf(mloc[r], v);
            }
#pragma unroll
        for (int r = 0; r < 4; r++) {
#pragma unroll
            for (int off = 1; off < 16; off <<= 1)
                mloc[r] = fmaxf(mloc[r], __shfl_xor(mloc[r], off));
            const float mn = fmaxf(m_i[r], mloc[r]);
            const float a = __builtin_exp2f(m_i[r] - mn);
            m_i[r] = mn;
            l_i[r] *= a;
#pragma unroll
            for (int ni = 0; ni < 4; ni++) o[ni][r] *= a;
        }
        float rs[4] = {0.f, 0.f, 0.f, 0.f};
#pragma unroll
        for (int ni = 0; ni < 4; ni++)
#pragma unroll
            for (int r = 0; r < 4; r++) {
                const float p = __builtin_exp2f(s[ni][r] - m_i[r]);
                rs[r] += p;
                Ps[wave][(al * 4 + r) * 72 + ni * 16 + ac] = f2bf(p);
            }
#pragma unroll
        for (int r = 0; r < 4; r++) {
#pragma unroll
            for (int off = 1; off < 16; off <<= 1) rs[r] += __shfl_xor(rs[r], off);
            l_i[r] += rs[r];
        }

        // prefetch bias for kb+1 (s[] now dead -> lower peak pressure)
        float bn[16];
        if (kbk < 31) {
#pragma unroll
            for (int ni = 0; ni < 4; ni++)
#pragma unroll
                for (int r = 0; r < 4; r++)
                    bn[ni * 4 + r] = bp[r * 2048 + k1 + ni * 16];
        }

        const bf16x8 pf0 = *(const bf16x8*)&Ps[wave][ac * 72 + al * 8];
        const bf16x8 pf1 = *(const bf16x8*)&Ps[wave][ac * 72 + al * 8 + 32];
#pragma unroll
        for (int ni = 0; ni < 4; ni++) {
            const bf16x8 vf0 = *(const bf16x8*)&Vs[(ni * 16 + ac) * 72 + al * 8];
            const bf16x8 vf1 =
                *(const bf16x8*)&Vs[(ni * 16 + ac) * 72 + al * 8 + 32];
            o[ni] = MFMA(pf0, vf0, o[ni]);
            o[ni] = MFMA(pf1, vf1, o[ni]);
        }
#pragma unroll
        for (int i = 0; i < 16; i++) bc[i] = bn[i];
    }

    const int b = bh >> 4, h = bh & 15;
#pragma unroll
    for (int r = 0; r < 4; r++) {
        const float inv = 1.f / l_i[r];
        const int qrow = q0 + wave * 16 + al * 4 + r;
#pragma unroll
        for (int ni = 0; ni < 4; ni++) {
            const int d = ni * 16 + ac;
            Ctx[((long long)(b * 2048 + qrow)) * 1024 + h * 64 + d] =
                f2bf(o[ni][r] * inv);
        }
    }
}

// ---------------- GEMM2: out = Ctx @ Wo^T + bo (fp32 out) ----------------
__global__ __launch_bounds__(256, 2) void gemm_out_kernel(
    const short* __restrict__ A, const short* __restrict__ W,
    const float* __restrict__ bias, float* __restrict__ out) {
    __shared__ short As[128 * 32];
    __shared__ short Bs[128 * 32];
    __shared__ float scrF[4][16 * 28];  // per-wave fp32 repack, stride 28
    const int tid = threadIdx.x;
    const int wave = tid >> 6, lane = tid & 63;
    const int al = lane >> 4, ac = lane & 15;
    const int m0 = blockIdx.x * 128;
    const int n0 = blockIdx.y * 128;
    const int wm = wave & 1, wn = wave >> 1;

    const int crow = tid >> 2, ccol = (tid & 3) * 8;
    const short* Ag0 = A + (m0 + crow) * 1024 + ccol;
    const short* Ag1 = A + (m0 + crow + 64) * 1024 + ccol;
    const short* Wg0 = W + (n0 + crow) * 1024 + ccol;
    const short* Wg1 = W + (n0 + crow + 64) * 1024 + ccol;
    short* lA0 = &As[wave * 512];
    short* lA1 = &As[2048 + wave * 512];
    short* lB0 = &Bs[wave * 512];
    short* lB1 = &Bs[2048 + wave * 512];

    f32x4 acc[4][4];
#pragma unroll
    for (int mi = 0; mi < 4; mi++)
#pragma unroll
        for (int ni = 0; ni < 4; ni++) acc[mi][ni] = (f32x4){0.f, 0.f, 0.f, 0.f};

    for (int k0 = 0; k0 < 1024; k0 += 32) {
        __syncthreads();
        g2l16(Ag0 + k0, lA0);
        g2l16(Ag1 + k0, lA1);
        g2l16(Wg0 + k0, lB0);
        g2l16(Wg1 + k0, lB1);
        __syncthreads();
        bf16x8 af[4], bfr[4];
#pragma unroll
        for (int i = 0; i < 4; i++) {
            af[i] = *(const bf16x8*)&As[(wm * 64 + i * 16 + ac) * 32 + al * 8];
            bfr[i] = *(const bf16x8*)&Bs[(wn * 64 + i * 16 + ac) * 32 + al * 8];
        }
#pragma unroll
        for (int mi = 0; mi < 4; mi++)
#pragma unroll
            for (int ni = 0; ni < 4; ni++)
                acc[mi][ni] = MFMA(af[mi], bfr[ni], acc[mi][ni]);
    }

    float* scr = scrF[wave];
    const int lr = lane >> 2, lq = lane & 3;
#pragma unroll
    for (int mi = 0; mi < 4; mi++) {
#pragma unroll
        for (int ni = 0; ni < 4; ni++) {
            const int col0 = n0 + wn * 64 + ni * 16;
            const float bvc = bias[col0 + ac];
#pragma unroll
            for (int r = 0; r < 4; r++)
                scr[(al * 4 + r) * 28 + ac] = acc[mi][ni][r] + bvc;
            f32x4 v4 = *(const f32x4*)&scr[lr * 28 + lq * 4];
            const int row = m0 + wm * 64 + mi * 16 + lr;
            *(f32x4*)&out[row * 1024 + col0 + lq * 4] = v4;
        }
    }
}

extern "C" void kernel_launch(void* const* d_in, const int* in_sizes, int n_in,
                              void* d_out, int out_size, void* d_ws,
                              size_t ws_size, hipStream_t stream) {
    const float* X = (const float*)d_in[0];
    const float* keb = (const float*)d_in[1];
    const float* Wi = (const float*)d_in[2];
    const float* bi = (const float*)d_in[3];
    const float* Wo = (const float*)d_in[4];
    const float* bo = (const float*)d_in[5];
    float* out = (float*)d_out;

    char* ws = (char*)d_ws;
    short* Xb  = (short*)(ws);              //  8 MB  [4096,1024]
    short* Wib = (short*)(ws + 8388608);    //  6 MB  [3072,1024]
    short* Wob = (short*)(ws + 14680064);   //  2 MB  [1024,1024]
    short* Qb  = (short*)(ws + 16777216);   //  8 MB  [bh][l][d] (pre-scaled)
    short* Kb  = (short*)(ws + 25165824);   //  8 MB  [bh][l][d]
    short* Vtb = (short*)(ws + 33554432);   //  8 MB  [bh][d][l]
    short* Ctx = (short*)(ws + 41943040);   //  8 MB  [4096,1024]

    cvt_bf16_kernel<<<dim3(524288 / 256), 256, 0, stream>>>(X, Xb, 524288);
    cvt_bf16_kernel<<<dim3(393216 / 256), 256, 0, stream>>>(Wi, Wib, 393216);
    cvt_bf16_kernel<<<dim3(131072 / 256), 256, 0, stream>>>(Wo, Wob, 131072);
    gemm_qkv_kernel<<<dim3(32, 24), 256, 0, stream>>>(Xb, Wib, bi, Qb, Kb, Vtb);
    attn_kernel<<<dim3(32, 32), 256, 0, stream>>>(Qb, Kb, Vtb, keb, Ctx);
    gemm_out_kernel<<<dim3(32, 8), 256, 0, stream>>>(Ctx, Wob, bo, out);
}